// Round 2
// baseline (1825.954 us; speedup 1.0000x reference)
//
#include <hip/hip_runtime.h>

// Problem: B=16, C=2048, HID=256, H=W=32 (HW=1024). All I/O fp32.
// out[:, 0:2048] = qf ; Q=W qf+b, K=W pf+b ; S=Q^T K ; softmax ; out[:, 2048:] = V A^T

#define NB   16
#define NC   2048
#define NHID 256
#define NHW  1024

// ---------------- concat first half: out[b, 0:2048, :] = qf ----------------
// input per batch: 2048*1024 floats = 2^19 uint4 ; output per batch: 2^20 uint4
__global__ __launch_bounds__(256) void copy_kernel(const uint4* __restrict__ qf,
                                                   uint4* __restrict__ out) {
    int idx = blockIdx.x * 256 + threadIdx.x;   // 16 * 2^19 = 8,388,608 uint4
    int b = idx >> 19;
    int r = idx & 0x7FFFF;
    out[((size_t)b << 20) + r] = qf[idx];
}

// ---------------- sentinel: zero the aligned half if workspace too small ----------------
__global__ __launch_bounds__(256) void zero_aligned_kernel(float4* __restrict__ out) {
    int idx = blockIdx.x * 256 + threadIdx.x;   // 16 * 2^19 = 8,388,608 float4
    int b = idx >> 19;
    int r = idx & 0x7FFFF;
    out[((size_t)b << 20) + (1 << 19) + r] = make_float4(0.f, 0.f, 0.f, 0.f);
}

// ---------------- projection: Q/K[o,hw] = sum_c W[o,c] X[c,hw] + bias[o] ----------------
// grid: (NHW/64, NHID/64, 2*nb); z < nb -> Q from qf, else K from pf
__global__ __launch_bounds__(256) void proj_kernel(
    const float* __restrict__ qf, const float* __restrict__ pf,
    const float* __restrict__ Wm, const float* __restrict__ bias,
    float* __restrict__ Qo, float* __restrict__ Ko, int b_base, int nb)
{
    const int z = blockIdx.z;
    const int which = (z >= nb) ? 1 : 0;
    const int zb = z - which * nb;
    const int b = b_base + zb;
    const float* X = (which ? pf : qf) + (size_t)b * NC * NHW;
    float* Out = (which ? Ko : Qo) + (size_t)zb * NHID * NHW;
    const int m0 = blockIdx.y * 64;   // over HID
    const int n0 = blockIdx.x * 64;   // over HW

    __shared__ float As[16][68];
    __shared__ float Bs[16][68];

    const int t  = threadIdx.x;
    const int tm = (t >> 4) << 2;
    const int tn = (t & 15) << 2;

    float acc[4][4] = {};

    for (int k0 = 0; k0 < NC; k0 += 16) {
        {   // A tile: W[m0+m, k0+kk..kk+3]  (row-major, kk contiguous)
            const int m  = t >> 2;
            const int kk = (t & 3) << 2;
            float4 v = *(const float4*)(Wm + (size_t)(m0 + m) * NC + k0 + kk);
            As[kk + 0][m] = v.x; As[kk + 1][m] = v.y;
            As[kk + 2][m] = v.z; As[kk + 3][m] = v.w;
        }
        {   // B tile: X[k0+kk, n0+n..n+3]  (n contiguous -> coalesced)
            const int kk = t >> 4;
            const int n  = (t & 15) << 2;
            *(float4*)&Bs[kk][n] = *(const float4*)(X + (size_t)(k0 + kk) * NHW + n0 + n);
        }
        __syncthreads();
        #pragma unroll
        for (int kk = 0; kk < 16; ++kk) {
            float a[4], q[4];
            #pragma unroll
            for (int i = 0; i < 4; ++i) a[i] = As[kk][tm + i];
            #pragma unroll
            for (int j = 0; j < 4; ++j) q[j] = Bs[kk][tn + j];
            #pragma unroll
            for (int i = 0; i < 4; ++i)
                #pragma unroll
                for (int j = 0; j < 4; ++j)
                    acc[i][j] = fmaf(a[i], q[j], acc[i][j]);
        }
        __syncthreads();
    }
    #pragma unroll
    for (int i = 0; i < 4; ++i) {
        float bv = bias[m0 + tm + i];
        float4 o;
        o.x = acc[i][0] + bv; o.y = acc[i][1] + bv;
        o.z = acc[i][2] + bv; o.w = acc[i][3] + bv;
        *(float4*)(Out + (size_t)(m0 + tm + i) * NHW + n0 + tn) = o;
    }
}

// ---------------- scores: S[q1,q2] = sum_o Q[o,q1] K[o,q2] ----------------
// grid: (NHW/64, NHW/64, nb)
__global__ __launch_bounds__(256) void scores_kernel(
    const float* __restrict__ Q, const float* __restrict__ K, float* __restrict__ S)
{
    const int zb = blockIdx.z;
    const float* Qb = Q + (size_t)zb * NHID * NHW;
    const float* Kb = K + (size_t)zb * NHID * NHW;
    float* Sb = S + (size_t)zb * NHW * NHW;
    const int m0 = blockIdx.y * 64;
    const int n0 = blockIdx.x * 64;

    __shared__ float As[16][68];
    __shared__ float Bs[16][68];

    const int t  = threadIdx.x;
    const int tm = (t >> 4) << 2;
    const int tn = (t & 15) << 2;

    float acc[4][4] = {};

    for (int k0 = 0; k0 < NHID; k0 += 16) {
        {   // A tile: Q[(k0+kk), m0+m..] (m contiguous -> coalesced float4)
            const int kk = t >> 4;
            const int m  = (t & 15) << 2;
            *(float4*)&As[kk][m] = *(const float4*)(Qb + (size_t)(k0 + kk) * NHW + m0 + m);
        }
        {   // B tile: K[(k0+kk), n0+n..]
            const int kk = t >> 4;
            const int n  = (t & 15) << 2;
            *(float4*)&Bs[kk][n] = *(const float4*)(Kb + (size_t)(k0 + kk) * NHW + n0 + n);
        }
        __syncthreads();
        #pragma unroll
        for (int kk = 0; kk < 16; ++kk) {
            float a[4], q[4];
            #pragma unroll
            for (int i = 0; i < 4; ++i) a[i] = As[kk][tm + i];
            #pragma unroll
            for (int j = 0; j < 4; ++j) q[j] = Bs[kk][tn + j];
            #pragma unroll
            for (int i = 0; i < 4; ++i)
                #pragma unroll
                for (int j = 0; j < 4; ++j)
                    acc[i][j] = fmaf(a[i], q[j], acc[i][j]);
        }
        __syncthreads();
    }
    #pragma unroll
    for (int i = 0; i < 4; ++i) {
        float4 o;
        o.x = acc[i][0]; o.y = acc[i][1]; o.z = acc[i][2]; o.w = acc[i][3];
        *(float4*)(Sb + (size_t)(m0 + tm + i) * NHW + n0 + tn) = o;
    }
}

// ---------------- softmax rows of S (length 1024), one wave per row ----------------
__global__ __launch_bounds__(256) void softmax_kernel(float* __restrict__ S) {
    const int t = threadIdx.x;
    const int wave = t >> 6;
    const int lane = t & 63;
    float* row = S + ((size_t)blockIdx.x * 4 + wave) * NHW;

    float4 v[4];
    float mx = -1e30f;
    #pragma unroll
    for (int j = 0; j < 4; ++j) {
        v[j] = *(const float4*)(row + (lane << 2) + (j << 8));
        mx = fmaxf(mx, fmaxf(fmaxf(v[j].x, v[j].y), fmaxf(v[j].z, v[j].w)));
    }
    #pragma unroll
    for (int off = 32; off >= 1; off >>= 1)
        mx = fmaxf(mx, __shfl_xor(mx, off, 64));

    float s = 0.f;
    #pragma unroll
    for (int j = 0; j < 4; ++j) {
        v[j].x = __expf(v[j].x - mx); v[j].y = __expf(v[j].y - mx);
        v[j].z = __expf(v[j].z - mx); v[j].w = __expf(v[j].w - mx);
        s += v[j].x + v[j].y + v[j].z + v[j].w;
    }
    #pragma unroll
    for (int off = 32; off >= 1; off >>= 1)
        s += __shfl_xor(s, off, 64);

    const float inv = 1.0f / s;
    #pragma unroll
    for (int j = 0; j < 4; ++j) {
        v[j].x *= inv; v[j].y *= inv; v[j].z *= inv; v[j].w *= inv;
        *(float4*)(row + (lane << 2) + (j << 8)) = v[j];
    }
}

// ---------------- AV: out[b, 2048+c, q] = sum_k V[c,k] A[q,k] ----------------
// grid: (NHW/64, NC/64, nb)
__global__ __launch_bounds__(256) void av_kernel(
    const float* __restrict__ pf, const float* __restrict__ S,
    float* __restrict__ out, int b_base)
{
    const int zb = blockIdx.z;
    const int b = b_base + zb;
    const float* Vb = pf + (size_t)b * NC * NHW;
    const float* Sb = S + (size_t)zb * NHW * NHW;
    float* Ob = out + (size_t)b * (2 * NC) * NHW + (size_t)NC * NHW;
    const int m0 = blockIdx.y * 64;   // over C
    const int n0 = blockIdx.x * 64;   // over q

    __shared__ float As[16][68];
    __shared__ float Bs[16][68];

    const int t  = threadIdx.x;
    const int tm = (t >> 4) << 2;
    const int tn = (t & 15) << 2;

    float acc[4][4] = {};

    for (int k0 = 0; k0 < NHW; k0 += 16) {
        {   // A tile: V[m0+m, k0+kk..] (kk contiguous)
            const int m  = t >> 2;
            const int kk = (t & 3) << 2;
            float4 v = *(const float4*)(Vb + (size_t)(m0 + m) * NHW + k0 + kk);
            As[kk + 0][m] = v.x; As[kk + 1][m] = v.y;
            As[kk + 2][m] = v.z; As[kk + 3][m] = v.w;
        }
        {   // B tile: A_soft[n0+n, k0+kk..] (kk contiguous)
            const int n  = t >> 2;
            const int kk = (t & 3) << 2;
            float4 v = *(const float4*)(Sb + (size_t)(n0 + n) * NHW + k0 + kk);
            Bs[kk + 0][n] = v.x; Bs[kk + 1][n] = v.y;
            Bs[kk + 2][n] = v.z; Bs[kk + 3][n] = v.w;
        }
        __syncthreads();
        #pragma unroll
        for (int kk = 0; kk < 16; ++kk) {
            float a[4], q[4];
            #pragma unroll
            for (int i = 0; i < 4; ++i) a[i] = As[kk][tm + i];
            #pragma unroll
            for (int j = 0; j < 4; ++j) q[j] = Bs[kk][tn + j];
            #pragma unroll
            for (int i = 0; i < 4; ++i)
                #pragma unroll
                for (int j = 0; j < 4; ++j)
                    acc[i][j] = fmaf(a[i], q[j], acc[i][j]);
        }
        __syncthreads();
    }
    #pragma unroll
    for (int i = 0; i < 4; ++i) {
        float4 o;
        o.x = acc[i][0]; o.y = acc[i][1]; o.z = acc[i][2]; o.w = acc[i][3];
        *(float4*)(Ob + (size_t)(m0 + tm + i) * NHW + n0 + tn) = o;
    }
}

extern "C" void kernel_launch(void* const* d_in, const int* in_sizes, int n_in,
                              void* d_out, int out_size, void* d_ws, size_t ws_size,
                              hipStream_t stream) {
    const float* qf   = (const float*)d_in[0];
    const float* pf   = (const float*)d_in[1];
    const float* Wm   = (const float*)d_in[2];
    const float* bias = (const float*)d_in[3];
    float* out = (float*)d_out;

    copy_kernel<<<32768, 256, 0, stream>>>((const uint4*)qf, (uint4*)out);

    const size_t fullQ = (size_t)NB * NHID * NHW;   // 4M floats
    const size_t fullS = (size_t)NB * NHW * NHW;    // 16M floats
    const size_t perQ  = (size_t)NHID * NHW;        // 256K floats
    const size_t perS  = (size_t)NHW * NHW;         // 1M floats

    if (ws_size >= (2 * fullQ + fullS) * sizeof(float)) {
        // full-batch pipeline (96 MiB workspace)
        float* Q = (float*)d_ws;
        float* K = Q + fullQ;
        float* S = K + fullQ;
        proj_kernel<<<dim3(16, 4, 32), 256, 0, stream>>>(qf, pf, Wm, bias, Q, K, 0, NB);
        scores_kernel<<<dim3(16, 16, 16), 256, 0, stream>>>(Q, K, S);
        softmax_kernel<<<NB * 256, 256, 0, stream>>>(S);
        av_kernel<<<dim3(16, 32, 16), 256, 0, stream>>>(pf, S, out, 0);
    } else if (ws_size >= (2 * perQ + perS) * sizeof(float)) {
        // per-batch fallback (6 MiB workspace)
        float* Q = (float*)d_ws;
        float* K = Q + perQ;
        float* S = K + perQ;
        for (int b = 0; b < NB; ++b) {
            proj_kernel<<<dim3(16, 4, 2), 256, 0, stream>>>(qf, pf, Wm, bias, Q, K, b, 1);
            scores_kernel<<<dim3(16, 16, 1), 256, 0, stream>>>(Q, K, S);
            softmax_kernel<<<256, 256, 0, stream>>>(S);
            av_kernel<<<dim3(16, 32, 1), 256, 0, stream>>>(pf, S, out, b);
        }
    } else {
        // SENTINEL: workspace too small for any path — write zeros to aligned half.
        // (err would show ~5.4 finite, telling us ws_size is the problem, not dtype)
        zero_aligned_kernel<<<32768, 256, 0, stream>>>((float4*)out);
    }
}

// Round 3
// 707.970 us; speedup vs baseline: 2.5791x; 2.5791x over previous
//
#include <hip/hip_runtime.h>

// B=16, C=2048, HID=256, HW=1024. fp32 I/O.
// out[:,0:2048]=qf ; Q^T/K^T=f16[hw][hid] via MFMA ; S=Q^T K (f32) ; softmax ; out[:,2048:]=V A^T
#define NB   16
#define NC   2048
#define NHID 256
#define NHW  1024
#define ROWH 36   // LDS row: 32 data halfs + 4 pad = 72 B (8B-aligned, bank-spread)

using half4_t  = __attribute__((ext_vector_type(4))) _Float16;
using half8_t  = __attribute__((ext_vector_type(8))) _Float16;
using float4_t = __attribute__((ext_vector_type(4))) float;

// ---------------- concat first half ----------------
__global__ __launch_bounds__(256) void copy_kernel(const uint4* __restrict__ qf,
                                                   uint4* __restrict__ out) {
    int idx = blockIdx.x * 256 + threadIdx.x;
    int b = idx >> 19;
    int r = idx & 0x7FFFF;
    out[((size_t)b << 20) + r] = qf[idx];
}

// ---------------- staging helpers (128 x 32 tile into LDS f16) ----------------
// natural [row][k], f32 source (pre-offset to tile row 0), stride in floats
__device__ __forceinline__ void stage_f32(const float* __restrict__ src, size_t stride,
                                          int k0, _Float16* __restrict__ dst, int t) {
    #pragma unroll
    for (int i = 0; i < 4; ++i) {
        int flat = i * 256 + t;
        int row = flat >> 3;
        int ch  = flat & 7;
        float4 v = *(const float4*)(src + (size_t)row * stride + k0 + ch * 4);
        half4_t h;
        h[0] = (_Float16)v.x; h[1] = (_Float16)v.y;
        h[2] = (_Float16)v.z; h[3] = (_Float16)v.w;
        *(half4_t*)(dst + row * ROWH + ch * 4) = h;
    }
}

// natural [row][k], f16 source
__device__ __forceinline__ void stage_f16(const _Float16* __restrict__ src, size_t stride,
                                          int k0, _Float16* __restrict__ dst, int t) {
    #pragma unroll
    for (int i = 0; i < 2; ++i) {
        int flat = i * 256 + t;
        int row = flat >> 2;
        int ch  = flat & 3;
        const _Float16* p = src + (size_t)row * stride + k0 + ch * 8;
        half4_t h0 = *(const half4_t*)p;
        half4_t h1 = *(const half4_t*)(p + 4);
        *(half4_t*)(dst + row * ROWH + ch * 8)     = h0;
        *(half4_t*)(dst + row * ROWH + ch * 8 + 4) = h1;
    }
}

// transposed: dst[m][k] = src[k][m]; f32 source pre-offset to column m0; stride in floats
__device__ __forceinline__ void stage_f32_T(const float* __restrict__ src, size_t stride,
                                            int k0, _Float16* __restrict__ dst, int t) {
    const int j = t & 31;   // m-group: m = j*4+e
    const int g = t >> 5;   // k-group: k = g*4+r
    float4 xr[4];
    #pragma unroll
    for (int r = 0; r < 4; ++r)
        xr[r] = *(const float4*)(src + (size_t)(k0 + g * 4 + r) * stride + j * 4);
    #pragma unroll
    for (int e = 0; e < 4; ++e) {
        half4_t h;
        h[0] = (_Float16)((&xr[0].x)[e]);
        h[1] = (_Float16)((&xr[1].x)[e]);
        h[2] = (_Float16)((&xr[2].x)[e]);
        h[3] = (_Float16)((&xr[3].x)[e]);
        *(half4_t*)(dst + (j * 4 + e) * ROWH + g * 4) = h;
    }
}

// ---------------- MFMA core: 4 waves, each 64x64 of the 128x128 tile ----------------
__device__ __forceinline__ void mfma_step(const _Float16* __restrict__ As,
                                          const _Float16* __restrict__ Bs,
                                          int wr, int wc, int quad, int l15,
                                          float4_t acc[4][4]) {
    half8_t af[4], bf[4];
    #pragma unroll
    for (int i = 0; i < 4; ++i) {
        const _Float16* pa = As + (wr + i * 16 + l15) * ROWH + quad * 8;
        half4_t a0 = *(const half4_t*)pa;
        half4_t a1 = *(const half4_t*)(pa + 4);
        const _Float16* pb = Bs + (wc + i * 16 + l15) * ROWH + quad * 8;
        half4_t b0 = *(const half4_t*)pb;
        half4_t b1 = *(const half4_t*)(pb + 4);
        #pragma unroll
        for (int e = 0; e < 4; ++e) {
            af[i][e] = a0[e]; af[i][4 + e] = a1[e];
            bf[i][e] = b0[e]; bf[i][4 + e] = b1[e];
        }
    }
    #pragma unroll
    for (int i = 0; i < 4; ++i)
        #pragma unroll
        for (int j = 0; j < 4; ++j)
            acc[i][j] = __builtin_amdgcn_mfma_f32_16x16x32_f16(af[i], bf[j], acc[i][j], 0, 0, 0);
}

#define ACC_INIT(acc) \
    _Pragma("unroll") for (int i_ = 0; i_ < 4; ++i_) \
    _Pragma("unroll") for (int j_ = 0; j_ < 4; ++j_) \
    _Pragma("unroll") for (int r_ = 0; r_ < 4; ++r_) acc[i_][j_][r_] = 0.f;

// ---------------- proj: Q^T[hw][hid] = X^T W^T + b ; D[m=hw][n=hid], K=C ----------------
// grid (2, 8, 32): z>=16 -> K from pf
__global__ __launch_bounds__(256) void proj16_kernel(
    const float* __restrict__ qf, const float* __restrict__ pf,
    const float* __restrict__ Wm, const float* __restrict__ bias,
    _Float16* __restrict__ Q16, _Float16* __restrict__ K16)
{
    __shared__ _Float16 As[128 * ROWH];
    __shared__ _Float16 Bs[128 * ROWH];
    const int z = blockIdx.z;
    const int which = z >> 4;
    const int b = z & 15;
    const float* X = (which ? pf : qf) + (size_t)b * NC * NHW;
    _Float16* O = (which ? K16 : Q16) + (size_t)b * NHW * NHID;
    const int m0 = blockIdx.y * 128;  // hw
    const int n0 = blockIdx.x * 128;  // hid
    const int t = threadIdx.x;
    const int w = t >> 6, l = t & 63, quad = l >> 4, l15 = l & 15;
    const int wr = (w >> 1) * 64, wc = (w & 1) * 64;

    float4_t acc[4][4];
    ACC_INIT(acc)

    for (int k0 = 0; k0 < NC; k0 += 32) {
        stage_f32_T(X + m0, NHW, k0, As, t);                 // A[m=hw][k=c] = X[c][hw]
        stage_f32(Wm + (size_t)n0 * NC, NC, k0, Bs, t);      // B[n=hid][k=c] = W natural
        __syncthreads();
        mfma_step(As, Bs, wr, wc, quad, l15, acc);
        __syncthreads();
    }
    float bv[4];
    #pragma unroll
    for (int j = 0; j < 4; ++j) bv[j] = bias[n0 + wc + j * 16 + l15];
    #pragma unroll
    for (int i = 0; i < 4; ++i)
        #pragma unroll
        for (int j = 0; j < 4; ++j)
            #pragma unroll
            for (int r = 0; r < 4; ++r) {
                int hw  = m0 + wr + i * 16 + quad * 4 + r;
                int hid = n0 + wc + j * 16 + l15;
                O[(size_t)hw * NHID + hid] = (_Float16)(acc[i][j][r] + bv[j]);
            }
}

// ---------------- scores: S[q1][q2] = sum_o Q^T[q1][o] K^T[q2][o] ; K=256 ----------------
// grid (8, 8, 16)
__global__ __launch_bounds__(256) void scores16_kernel(
    const _Float16* __restrict__ Q16, const _Float16* __restrict__ K16,
    float* __restrict__ S)
{
    __shared__ _Float16 As[128 * ROWH];
    __shared__ _Float16 Bs[128 * ROWH];
    const int b = blockIdx.z;
    const _Float16* Qb = Q16 + (size_t)b * NHW * NHID;
    const _Float16* Kb = K16 + (size_t)b * NHW * NHID;
    float* Sb = S + (size_t)b * NHW * NHW;
    const int m0 = blockIdx.y * 128;  // q1
    const int n0 = blockIdx.x * 128;  // q2
    const int t = threadIdx.x;
    const int w = t >> 6, l = t & 63, quad = l >> 4, l15 = l & 15;
    const int wr = (w >> 1) * 64, wc = (w & 1) * 64;

    float4_t acc[4][4];
    ACC_INIT(acc)

    for (int k0 = 0; k0 < NHID; k0 += 32) {
        stage_f16(Qb + (size_t)m0 * NHID, NHID, k0, As, t);
        stage_f16(Kb + (size_t)n0 * NHID, NHID, k0, Bs, t);
        __syncthreads();
        mfma_step(As, Bs, wr, wc, quad, l15, acc);
        __syncthreads();
    }
    #pragma unroll
    for (int i = 0; i < 4; ++i)
        #pragma unroll
        for (int j = 0; j < 4; ++j)
            #pragma unroll
            for (int r = 0; r < 4; ++r) {
                int q1 = m0 + wr + i * 16 + quad * 4 + r;
                int q2 = n0 + wc + j * 16 + l15;
                Sb[(size_t)q1 * NHW + q2] = acc[i][j][r];
            }
}

// ---------------- softmax rows of S (length 1024), one wave per row, in-place f32 ----------------
__global__ __launch_bounds__(256) void softmax_kernel(float* __restrict__ S) {
    const int t = threadIdx.x;
    const int wave = t >> 6;
    const int lane = t & 63;
    float* row = S + ((size_t)blockIdx.x * 4 + wave) * NHW;

    float4 v[4];
    float mx = -1e30f;
    #pragma unroll
    for (int j = 0; j < 4; ++j) {
        v[j] = *(const float4*)(row + (lane << 2) + (j << 8));
        mx = fmaxf(mx, fmaxf(fmaxf(v[j].x, v[j].y), fmaxf(v[j].z, v[j].w)));
    }
    #pragma unroll
    for (int off = 32; off >= 1; off >>= 1)
        mx = fmaxf(mx, __shfl_xor(mx, off, 64));

    float s = 0.f;
    #pragma unroll
    for (int j = 0; j < 4; ++j) {
        v[j].x = __expf(v[j].x - mx); v[j].y = __expf(v[j].y - mx);
        v[j].z = __expf(v[j].z - mx); v[j].w = __expf(v[j].w - mx);
        s += v[j].x + v[j].y + v[j].z + v[j].w;
    }
    #pragma unroll
    for (int off = 32; off >= 1; off >>= 1)
        s += __shfl_xor(s, off, 64);

    const float inv = 1.0f / s;
    #pragma unroll
    for (int j = 0; j < 4; ++j) {
        v[j].x *= inv; v[j].y *= inv; v[j].z *= inv; v[j].w *= inv;
        *(float4*)(row + (lane << 2) + (j << 8)) = v[j];
    }
}

// ---------------- AV: out[b,2048+c,q] = sum_k V[c][k] A[q][k] ; K=1024 ----------------
// grid (8, 16, 16)
__global__ __launch_bounds__(256) void av16_kernel(
    const float* __restrict__ pf, const float* __restrict__ S,
    float* __restrict__ out)
{
    __shared__ _Float16 As[128 * ROWH];
    __shared__ _Float16 Bs[128 * ROWH];
    const int b = blockIdx.z;
    const float* Vb = pf + (size_t)b * NC * NHW;
    const float* Ab = S + (size_t)b * NHW * NHW;
    float* Ob = out + (size_t)b * (2 * NC) * NHW + (size_t)NC * NHW;
    const int m0 = blockIdx.y * 128;  // c
    const int n0 = blockIdx.x * 128;  // q
    const int t = threadIdx.x;
    const int w = t >> 6, l = t & 63, quad = l >> 4, l15 = l & 15;
    const int wr = (w >> 1) * 64, wc = (w & 1) * 64;

    float4_t acc[4][4];
    ACC_INIT(acc)

    for (int k0 = 0; k0 < NHW; k0 += 32) {
        stage_f32(Vb + (size_t)m0 * NHW, NHW, k0, As, t);   // A[m=c][k]
        stage_f32(Ab + (size_t)n0 * NHW, NHW, k0, Bs, t);   // B[n=q][k]
        __syncthreads();
        mfma_step(As, Bs, wr, wc, quad, l15, acc);
        __syncthreads();
    }
    #pragma unroll
    for (int i = 0; i < 4; ++i)
        #pragma unroll
        for (int j = 0; j < 4; ++j)
            #pragma unroll
            for (int r = 0; r < 4; ++r) {
                int c = m0 + wr + i * 16 + quad * 4 + r;
                int q = n0 + wc + j * 16 + l15;
                Ob[(size_t)c * NHW + q] = acc[i][j][r];
            }
}

extern "C" void kernel_launch(void* const* d_in, const int* in_sizes, int n_in,
                              void* d_out, int out_size, void* d_ws, size_t ws_size,
                              hipStream_t stream) {
    const float* qf   = (const float*)d_in[0];
    const float* pf   = (const float*)d_in[1];
    const float* Wm   = (const float*)d_in[2];
    const float* bias = (const float*)d_in[3];
    float* out = (float*)d_out;

    copy_kernel<<<32768, 256, 0, stream>>>((const uint4*)qf, (uint4*)out);

    const size_t q16elems = (size_t)NB * NHW * NHID;          // 4M halfs
    _Float16* Q16 = (_Float16*)d_ws;
    _Float16* K16 = Q16 + q16elems;
    float* S = (float*)((char*)d_ws + 2 * q16elems * sizeof(_Float16)); // +16 MiB, 64 MiB

    proj16_kernel<<<dim3(2, 8, 32), 256, 0, stream>>>(qf, pf, Wm, bias, Q16, K16);
    scores16_kernel<<<dim3(8, 8, 16), 256, 0, stream>>>(Q16, K16, S);
    softmax_kernel<<<NB * 256, 256, 0, stream>>>(S);
    av16_kernel<<<dim3(8, 16, 16), 256, 0, stream>>>(pf, S, out);
}